// Round 5
// baseline (306.328 us; speedup 1.0000x reference)
//
#include <hip/hip_runtime.h>
#include <cstddef>
#include <stdint.h>

#define HYP_C   0.1f
#define SQRT_C  0.31622776601683794f
#define CLIP_R  2.3f
#define MRG     0.1f
#define NPROX   256
#define DIM     128

// workspace layout (float offsets)
#define OFF_LH   0         // lh row-major      [256][128]
#define OFF_LHT  32768     // lh transposed     [128][256]
#define OFF_LN2  65536     // ||lh_m||^2        [256]
#define OFF_D1   65792     // dist(z, lh)       [1024][256]
#define OFF_D2   327936    // dist(lh, lh)      [256][256]
#define OFF_D3   393472    // dist(t, lh)       [1024][256]

// ---------------------------------------------------------------------------
// Kernel A: to_poincare(lcas) -> lh, lhT, ln2 ; also zero d_out
// ---------------------------------------------------------------------------
__global__ __launch_bounds__(128)
void to_poincare_kernel(const float* __restrict__ lcas,
                        float* __restrict__ ws,
                        float* __restrict__ out)
{
    const int row = blockIdx.x;
    const int k   = threadIdx.x;
    if (row == 0 && k == 0) out[0] = 0.0f;

    float v  = lcas[row * DIM + k];
    float ss = v * v;
    #pragma unroll
    for (int off = 32; off >= 1; off >>= 1)
        ss += __shfl_xor(ss, off, 64);
    __shared__ float wpart[2];
    if ((k & 63) == 0) wpart[k >> 6] = ss;
    __syncthreads();
    const float sumsq = wpart[0] + wpart[1];

    const float s1 = sqrtf(sumsq);
    const float xn = s1 + 1e-5f;
    const float f1 = fminf(1.0f, CLIP_R / xn);
    const float xn2 = fmaxf(f1 * s1, 1e-5f);
    const float th  = tanhf(SQRT_C * xn2);
    const float f2  = th / (SQRT_C * xn2);
    const float nr      = fmaxf(f2 * f1 * s1, 1e-5f);
    const float maxnorm = (1.0f - 1e-3f) / SQRT_C;
    const float f3      = (nr > maxnorm) ? (maxnorm / nr) : 1.0f;

    const float f  = f3 * f2 * f1;
    const float lv = f * v;
    ws[OFF_LH  + row * DIM + k]   = lv;
    ws[OFF_LHT + k * NPROX + row] = lv;
    if (k == 0) ws[OFF_LN2 + row] = f * f * sumsq;
}

// ---------------------------------------------------------------------------
// Kernel B: all three distance matrices in one launch. 4 rows/block.
// ---------------------------------------------------------------------------
__global__ __launch_bounds__(256)
void dist_all_kernel(const float* __restrict__ z,
                     const float* __restrict__ t,
                     float* __restrict__ ws, int nb1)
{
    const float* lhT = ws + OFF_LHT;
    const float* ln2 = ws + OFF_LN2;

    int b = blockIdx.x;
    const float* X; float* Dout; int row0;
    if (b < nb1)            { X = z;            Dout = ws + OFF_D1; row0 = b * 4; }
    else if (b < nb1 + 64)  { X = ws + OFF_LH;  Dout = ws + OFF_D2; row0 = (b - nb1) * 4; }
    else                    { X = t;            Dout = ws + OFF_D3; row0 = (b - nb1 - 64) * 4; }

    __shared__ float xs[4][DIM];
    __shared__ float sx2[4];

    for (int idx = threadIdx.x; idx < 4 * DIM; idx += 256)
        xs[idx / DIM][idx % DIM] = X[row0 * DIM + idx];
    __syncthreads();

    const int wid  = threadIdx.x >> 6;
    const int lane = threadIdx.x & 63;
    {
        float a = xs[wid][lane];
        float c = xs[wid][lane + 64];
        float s = a * a + c * c;
        #pragma unroll
        for (int off = 32; off >= 1; off >>= 1)
            s += __shfl_xor(s, off, 64);
        if (lane == 0) sx2[wid] = s;
    }
    __syncthreads();

    const int m = threadIdx.x;
    float dot0 = 0.f, dot1 = 0.f, dot2 = 0.f, dot3 = 0.f;
    #pragma unroll 8
    for (int k = 0; k < DIM; k += 4) {
        const float4 x0 = *(const float4*)&xs[0][k];
        const float4 x1 = *(const float4*)&xs[1][k];
        const float4 x2 = *(const float4*)&xs[2][k];
        const float4 x3 = *(const float4*)&xs[3][k];
        const float l0 = lhT[(k + 0) * NPROX + m];
        const float l1 = lhT[(k + 1) * NPROX + m];
        const float l2 = lhT[(k + 2) * NPROX + m];
        const float l3 = lhT[(k + 3) * NPROX + m];
        dot0 = fmaf(x0.x, l0, fmaf(x0.y, l1, fmaf(x0.z, l2, fmaf(x0.w, l3, dot0))));
        dot1 = fmaf(x1.x, l0, fmaf(x1.y, l1, fmaf(x1.z, l2, fmaf(x1.w, l3, dot1))));
        dot2 = fmaf(x2.x, l0, fmaf(x2.y, l1, fmaf(x2.z, l2, fmaf(x2.w, l3, dot2))));
        dot3 = fmaf(x3.x, l0, fmaf(x3.y, l1, fmaf(x3.z, l2, fmaf(x3.w, l3, dot3))));
    }

    const float y2 = ln2[m];
    float dots[4] = {dot0, dot1, dot2, dot3};
    #pragma unroll
    for (int r = 0; r < 4; ++r) {
        const float x2 = sx2[r];
        const float xy = -dots[r];
        const float a  = 1.0f + 2.0f * HYP_C * xy + HYP_C * y2;
        const float bb = 1.0f - HYP_C * x2;
        const float denom  = 1.0f + 2.0f * HYP_C * xy + HYP_C * HYP_C * x2 * y2;
        const float num_sq = a * a * x2 + 2.0f * a * bb * xy + bb * bb * y2;
        const float nrm = sqrtf(fmaxf(num_sq, 1e-12f)) / fabsf(denom + 1e-5f);
        float u = SQRT_C * nrm;
        u = fminf(fmaxf(u, -1.0f + 1e-5f), 1.0f - 1e-5f);
        const float d = (2.0f / SQRT_C) * (0.5f * (log1pf(u) - log1pf(-u)));
        Dout[(size_t)(row0 + r) * NPROX + m] = d;
    }
}

// ---------------------------------------------------------------------------
// Kernel C v5: wave-per-triplet, LDS staging via global_load_lds, DEPTH-3
// rotating buffers (each tile gets ~2 full steps of prefetch lead to cover
// L3/HBM latency on the g-stream). Issue-before-wait: each step first
// issues tile t+2's 5 DMAs, then waits vmcnt(10) (in-order retirement =>
// oldest 5 = tile t landed). Tail uses exact counts (5, then 0); never a
// mid-loop drain. Payloads extracted in-register via dynamic-lane shfl.
// 128-thread blocks (2 waves), LDS = 2 x 3 x 5KB = 30720 B -> 5 blocks/CU.
// ---------------------------------------------------------------------------
__device__ __forceinline__ float dpp_fmax16(float x) {
    int o;
    o = __builtin_amdgcn_update_dpp(0, __float_as_int(x), 0x121, 0xF, 0xF, true);
    x = fmaxf(x, __int_as_float(o));
    o = __builtin_amdgcn_update_dpp(0, __float_as_int(x), 0x122, 0xF, 0xF, true);
    x = fmaxf(x, __int_as_float(o));
    o = __builtin_amdgcn_update_dpp(0, __float_as_int(x), 0x124, 0xF, 0xF, true);
    x = fmaxf(x, __int_as_float(o));
    o = __builtin_amdgcn_update_dpp(0, __float_as_int(x), 0x128, 0xF, 0xF, true);
    x = fmaxf(x, __int_as_float(o));
    return x;
}

__device__ __forceinline__ int dpp_imin16(int x) {
    int o;
    o = __builtin_amdgcn_update_dpp(0, x, 0x121, 0xF, 0xF, true); x = min(x, o);
    o = __builtin_amdgcn_update_dpp(0, x, 0x122, 0xF, 0xF, true); x = min(x, o);
    o = __builtin_amdgcn_update_dpp(0, x, 0x124, 0xF, 0xF, true); x = min(x, o);
    o = __builtin_amdgcn_update_dpp(0, x, 0x128, 0xF, 0xF, true); x = min(x, o);
    return x;
}

__device__ __forceinline__ float wave_fmax(float x) {
    x = dpp_fmax16(x);
    x = fmaxf(x, __shfl_xor(x, 16, 64));
    x = fmaxf(x, __shfl_xor(x, 32, 64));
    return x;
}

__device__ __forceinline__ int wave_imin(int x) {
    x = dpp_imin16(x);
    x = min(x, __shfl_xor(x, 16, 64));
    x = min(x, __shfl_xor(x, 32, 64));
    return x;
}

// async 1KB row: lane l moves bytes [16l,16l+16) of src to lds_dst + 16l
__device__ __forceinline__ void ld_row_async(const float* src, const float* lds_dst, int lane) {
    typedef __attribute__((address_space(3))) uint32_t as3_u32;
    typedef const __attribute__((address_space(1))) uint32_t as1_u32;
    __builtin_amdgcn_global_load_lds((as1_u32*)(src + 4 * lane),
                                     (as3_u32*)(uint32_t)(uintptr_t)lds_dst,
                                     16, 0, 0);
}

// select element c (0..3, wave-uniform) of a float4
__device__ __forceinline__ float sel4(const float4 v, int c) {
    const float lo = (c & 1) ? v.y : v.x;
    const float hi = (c & 1) ? v.w : v.z;
    return (c & 2) ? hi : lo;
}

__global__ __launch_bounds__(128)
void ghhc_fused_kernel(const float* __restrict__ Da, const float* __restrict__ Db,
                       const float* __restrict__ Dc, const float* __restrict__ Dd,
                       const int* __restrict__ ta, const int* __restrict__ tb,
                       const int* __restrict__ tc, const int* __restrict__ td,
                       const float* __restrict__ ga, const float* __restrict__ gb,
                       const float* __restrict__ gc, const float* __restrict__ gd,
                       int Ta, int Tb, int Tc, int Td,
                       float sa, float sb, float sc_, float sd,
                       int nba, int nbb, int nbc,
                       float* __restrict__ out)
{
    const int tid  = threadIdx.x;
    const int w    = tid >> 6;
    const int lane = tid & 63;

    const int b = blockIdx.x;
    const float* D; const int* tr; const float* g; int Tt; float sc; int lb;
    if (b < nba)                   { D = Da; tr = ta; g = ga; Tt = Ta; sc = sa;  lb = b; }
    else if (b < nba + nbb)        { D = Db; tr = tb; g = gb; Tt = Tb; sc = sb;  lb = b - nba; }
    else if (b < nba + nbb + nbc)  { D = Dc; tr = tc; g = gc; Tt = Tc; sc = sc_; lb = b - nba - nbb; }
    else                           { D = Dd; tr = td; g = gd; Tt = Td; sc = sd;  lb = b - nba - nbb - nbc; }

    const int tstart = lb * 32 + w * 16;   // this wave's 16 consecutive triplets

    // lanes 0-15 hold the 16 triplet indices (lanes 16+ replicate)
    int tl = tstart + (lane & 15);
    tl = (tl < Tt) ? tl : (Tt - 1);
    const int idxi = tr[tl];
    const int idxj = tr[Tt + tl];
    const int idxk = tr[2 * Tt + tl];

    // per-wave LDS triple buffer: 3 x 5 rows x 256 floats (15360 B / wave)
    __shared__ __align__(16) float sbuf[2 * 3 * 5 * 256];   // 30720 B
    __shared__ float wsum[2];
    float* const wbase = sbuf + w * 3840;

    #define ISSUE(IT) { \
        const int t_  = tstart + (IT); \
        const int te_ = (t_ < Tt) ? t_ : (Tt - 1); \
        const int i_  = __shfl(idxi, (IT) & 15, 64); \
        const int j_  = __shfl(idxj, (IT) & 15, 64); \
        const int k_  = __shfl(idxk, (IT) & 15, 64); \
        float* B_ = wbase + ((IT) % 3) * 1280; \
        ld_row_async(D + (size_t)i_ * NPROX,          B_ +    0, lane); \
        ld_row_async(D + (size_t)j_ * NPROX,          B_ +  256, lane); \
        ld_row_async(D + (size_t)k_ * NPROX,          B_ +  512, lane); \
        ld_row_async(g + (size_t)te_ * NPROX,         B_ +  768, lane); \
        ld_row_async(g + ((size_t)Tt + te_) * NPROX,  B_ + 1024, lane); \
    }

    float acc = 0.0f;

    ISSUE(0); ISSUE(1);

    #define STEP(IT, VM) { \
        if ((IT) + 2 < 16) ISSUE((IT) + 2) \
        asm volatile("s_waitcnt vmcnt(" VM ")" ::: "memory"); \
        __builtin_amdgcn_sched_barrier(0); \
        const float* B_ = wbase + ((IT) % 3) * 1280; \
        const float4 di = ((const float4*)(B_ +    0))[lane]; \
        const float4 dj = ((const float4*)(B_ +  256))[lane]; \
        const float4 dk = ((const float4*)(B_ +  512))[lane]; \
        const float4 q0 = ((const float4*)(B_ +  768))[lane]; \
        const float4 q1 = ((const float4*)(B_ + 1024))[lane]; \
        float S0, S1, S2, S3, U0, U1, U2, U3; \
        { float m1, m2; \
          m1 = fmaxf(di.x, dj.x); S0 = fmaf(m1, -10.0f, q0.x); m2 = fmaxf(dk.x, m1); U0 = fmaf(m2, -10.0f, q1.x); \
          m1 = fmaxf(di.y, dj.y); S1 = fmaf(m1, -10.0f, q0.y); m2 = fmaxf(dk.y, m1); U1 = fmaf(m2, -10.0f, q1.y); \
          m1 = fmaxf(di.z, dj.z); S2 = fmaf(m1, -10.0f, q0.z); m2 = fmaxf(dk.z, m1); U2 = fmaf(m2, -10.0f, q1.z); \
          m1 = fmaxf(di.w, dj.w); S3 = fmaf(m1, -10.0f, q0.w); m2 = fmaxf(dk.w, m1); U3 = fmaf(m2, -10.0f, q1.w); } \
        const float gvA = wave_fmax(fmaxf(fmaxf(S0, S1), fmaxf(S2, S3))); \
        const float gvB = wave_fmax(fmaxf(fmaxf(U0, U1), fmaxf(U2, U3))); \
        int slA = 4, slB = 4; \
        slA = (S3 == gvA) ? 3 : slA; slA = (S2 == gvA) ? 2 : slA; \
        slA = (S1 == gvA) ? 1 : slA; slA = (S0 == gvA) ? 0 : slA; \
        slB = (U3 == gvB) ? 3 : slB; slB = (U2 == gvB) ? 2 : slB; \
        slB = (U1 == gvB) ? 1 : slB; slB = (U0 == gvB) ? 0 : slB; \
        const int eA = (slA < 4) ? ((lane << 2) | slA) : 1024; \
        const int eB = (slB < 4) ? ((lane << 2) | slB) : 1024; \
        const int Ag = wave_imin(eA); \
        const int Bg = wave_imin(eB); \
        const int lA = Ag >> 2, cA = Ag & 3; \
        const int lB = Bg >> 2, cB = Bg & 3; \
        const float diA = __shfl(sel4(di, cA), lA, 64); \
        const float djA = __shfl(sel4(dj, cA), lA, 64); \
        const float dkA = __shfl(sel4(dk, cA), lA, 64); \
        const float diB = __shfl(sel4(di, cB), lB, 64); \
        const float djB = __shfl(sel4(dj, cB), lB, 64); \
        const float dkB = __shfl(sel4(dk, cB), lB, 64); \
        const float hc = fmaxf(diA - diB + MRG, 0.0f) \
                       + fmaxf(djA - djB + MRG, 0.0f) \
                       + fmaxf(dkB - dkA + MRG, 0.0f); \
        acc += (((tstart + (IT)) < Tt) && (Ag != Bg) && lane == 0) ? hc * sc : 0.0f; \
    }

    STEP(0,"10")  STEP(1,"10")  STEP(2,"10")  STEP(3,"10")
    STEP(4,"10")  STEP(5,"10")  STEP(6,"10")  STEP(7,"10")
    STEP(8,"10")  STEP(9,"10")  STEP(10,"10") STEP(11,"10")
    STEP(12,"10") STEP(13,"10") STEP(14,"5")  STEP(15,"0")

    #undef STEP
    #undef ISSUE

    if (lane == 0) wsum[w] = acc;
    __syncthreads();
    if (tid == 0)
        atomicAdd(out, wsum[0] + wsum[1]);
}

// ---------------------------------------------------------------------------
extern "C" void kernel_launch(void* const* d_in, const int* in_sizes, int n_in,
                              void* d_out, int out_size, void* d_ws, size_t ws_size,
                              hipStream_t stream)
{
    const float* z_s  = (const float*)d_in[0];
    const float* t_s  = (const float*)d_in[1];
    const float* lcas = (const float*)d_in[3];
    const int* trip1 = (const int*)d_in[4];
    const int* trip2 = (const int*)d_in[5];
    const int* trip3 = (const int*)d_in[6];
    const int* trip4 = (const int*)d_in[7];
    const float* g1 = (const float*)d_in[8];
    const float* g2 = (const float*)d_in[9];
    const float* g3 = (const float*)d_in[10];
    const float* g4 = (const float*)d_in[11];
    float* out = (float*)d_out;
    float* ws  = (float*)d_ws;

    const int T1 = in_sizes[4] / 3;   // 51200
    const int T2 = in_sizes[5] / 3;   // 12800
    const int T3 = in_sizes[6] / 3;   // 51200
    const int T4 = in_sizes[7] / 3;   // 12800
    const int BS = in_sizes[0] / DIM; // 1024
    const int nb1 = BS / 4;

    to_poincare_kernel<<<NPROX, 128, 0, stream>>>(lcas, ws, out);

    dist_all_kernel<<<2 * nb1 + 64, 256, 0, stream>>>(z_s, t_s, ws, nb1);

    // 32 triplets per block (2 waves x 16 triplets each)
    const int nbA = (T1 + 31) / 32;   // 1600
    const int nbB = (T2 + 31) / 32;   // 400
    const int nbC = (T3 + 31) / 32;   // 1600
    const int nbD = (T4 + 31) / 32;   // 400
    ghhc_fused_kernel<<<nbA + nbB + nbC + nbD, 128, 0, stream>>>(
        ws + OFF_D1, ws + OFF_D2, ws + OFF_D3, ws + OFF_D2,
        trip1, trip2, trip3, trip4,
        g1, g2, g3, g4,
        T1, T2, T3, T4,
        1.0f / (float)T1, 1.0f / (float)T2, 1.0f / (float)T3, 1.0f / (float)T4,
        nbA, nbB, nbC,
        out);
}

// Round 6
// 304.898 us; speedup vs baseline: 1.0047x; 1.0047x over previous
//
#include <hip/hip_runtime.h>
#include <cstddef>
#include <stdint.h>

#define HYP_C   0.1f
#define SQRT_C  0.31622776601683794f
#define CLIP_R  2.3f
#define MRG     0.1f
#define NPROX   256
#define DIM     128

// workspace layout (float offsets)
#define OFF_LH   0         // lh row-major      [256][128]
#define OFF_LHT  32768     // lh transposed     [128][256]
#define OFF_LN2  65536     // ||lh_m||^2        [256]
#define OFF_D1   65792     // dist(z, lh)       [1024][256]
#define OFF_D2   327936    // dist(lh, lh)      [256][256]
#define OFF_D3   393472    // dist(t, lh)       [1024][256]

// ---------------------------------------------------------------------------
// Kernel A: to_poincare(lcas) -> lh, lhT, ln2 ; also zero d_out
// ---------------------------------------------------------------------------
__global__ __launch_bounds__(128)
void to_poincare_kernel(const float* __restrict__ lcas,
                        float* __restrict__ ws,
                        float* __restrict__ out)
{
    const int row = blockIdx.x;
    const int k   = threadIdx.x;
    if (row == 0 && k == 0) out[0] = 0.0f;

    float v  = lcas[row * DIM + k];
    float ss = v * v;
    #pragma unroll
    for (int off = 32; off >= 1; off >>= 1)
        ss += __shfl_xor(ss, off, 64);
    __shared__ float wpart[2];
    if ((k & 63) == 0) wpart[k >> 6] = ss;
    __syncthreads();
    const float sumsq = wpart[0] + wpart[1];

    const float s1 = sqrtf(sumsq);
    const float xn = s1 + 1e-5f;
    const float f1 = fminf(1.0f, CLIP_R / xn);
    const float xn2 = fmaxf(f1 * s1, 1e-5f);
    const float th  = tanhf(SQRT_C * xn2);
    const float f2  = th / (SQRT_C * xn2);
    const float nr      = fmaxf(f2 * f1 * s1, 1e-5f);
    const float maxnorm = (1.0f - 1e-3f) / SQRT_C;
    const float f3      = (nr > maxnorm) ? (maxnorm / nr) : 1.0f;

    const float f  = f3 * f2 * f1;
    const float lv = f * v;
    ws[OFF_LH  + row * DIM + k]   = lv;
    ws[OFF_LHT + k * NPROX + row] = lv;
    if (k == 0) ws[OFF_LN2 + row] = f * f * sumsq;
}

// ---------------------------------------------------------------------------
// Kernel B: all three distance matrices in one launch. 4 rows/block.
// ---------------------------------------------------------------------------
__global__ __launch_bounds__(256)
void dist_all_kernel(const float* __restrict__ z,
                     const float* __restrict__ t,
                     float* __restrict__ ws, int nb1)
{
    const float* lhT = ws + OFF_LHT;
    const float* ln2 = ws + OFF_LN2;

    int b = blockIdx.x;
    const float* X; float* Dout; int row0;
    if (b < nb1)            { X = z;            Dout = ws + OFF_D1; row0 = b * 4; }
    else if (b < nb1 + 64)  { X = ws + OFF_LH;  Dout = ws + OFF_D2; row0 = (b - nb1) * 4; }
    else                    { X = t;            Dout = ws + OFF_D3; row0 = (b - nb1 - 64) * 4; }

    __shared__ float xs[4][DIM];
    __shared__ float sx2[4];

    for (int idx = threadIdx.x; idx < 4 * DIM; idx += 256)
        xs[idx / DIM][idx % DIM] = X[row0 * DIM + idx];
    __syncthreads();

    const int wid  = threadIdx.x >> 6;
    const int lane = threadIdx.x & 63;
    {
        float a = xs[wid][lane];
        float c = xs[wid][lane + 64];
        float s = a * a + c * c;
        #pragma unroll
        for (int off = 32; off >= 1; off >>= 1)
            s += __shfl_xor(s, off, 64);
        if (lane == 0) sx2[wid] = s;
    }
    __syncthreads();

    const int m = threadIdx.x;
    float dot0 = 0.f, dot1 = 0.f, dot2 = 0.f, dot3 = 0.f;
    #pragma unroll 8
    for (int k = 0; k < DIM; k += 4) {
        const float4 x0 = *(const float4*)&xs[0][k];
        const float4 x1 = *(const float4*)&xs[1][k];
        const float4 x2 = *(const float4*)&xs[2][k];
        const float4 x3 = *(const float4*)&xs[3][k];
        const float l0 = lhT[(k + 0) * NPROX + m];
        const float l1 = lhT[(k + 1) * NPROX + m];
        const float l2 = lhT[(k + 2) * NPROX + m];
        const float l3 = lhT[(k + 3) * NPROX + m];
        dot0 = fmaf(x0.x, l0, fmaf(x0.y, l1, fmaf(x0.z, l2, fmaf(x0.w, l3, dot0))));
        dot1 = fmaf(x1.x, l0, fmaf(x1.y, l1, fmaf(x1.z, l2, fmaf(x1.w, l3, dot1))));
        dot2 = fmaf(x2.x, l0, fmaf(x2.y, l1, fmaf(x2.z, l2, fmaf(x2.w, l3, dot2))));
        dot3 = fmaf(x3.x, l0, fmaf(x3.y, l1, fmaf(x3.z, l2, fmaf(x3.w, l3, dot3))));
    }

    const float y2 = ln2[m];
    float dots[4] = {dot0, dot1, dot2, dot3};
    #pragma unroll
    for (int r = 0; r < 4; ++r) {
        const float x2 = sx2[r];
        const float xy = -dots[r];
        const float a  = 1.0f + 2.0f * HYP_C * xy + HYP_C * y2;
        const float bb = 1.0f - HYP_C * x2;
        const float denom  = 1.0f + 2.0f * HYP_C * xy + HYP_C * HYP_C * x2 * y2;
        const float num_sq = a * a * x2 + 2.0f * a * bb * xy + bb * bb * y2;
        const float nrm = sqrtf(fmaxf(num_sq, 1e-12f)) / fabsf(denom + 1e-5f);
        float u = SQRT_C * nrm;
        u = fminf(fmaxf(u, -1.0f + 1e-5f), 1.0f - 1e-5f);
        const float d = (2.0f / SQRT_C) * (0.5f * (log1pf(u) - log1pf(-u)));
        Dout[(size_t)(row0 + r) * NPROX + m] = d;
    }
}

// ---------------------------------------------------------------------------
// Kernel C v6: DUAL-PATH staging. D rows (L2-hot gathers, 3 KB/triplet) go
// down the VGPR-return path (depth-3 rotating register buffers); g rows
// (HBM stream, 2 KB/triplet) go down the global_load_lds DMA path (depth-4
// LDS slots). One shared in-order vmcnt FIFO; issue order pinned with
// sched_barrier(0) fences; one counted wait per step (vmcnt(12) steady
// state; exact prologue/tail counts derived from FIFO position of D(t),
// the latest-needed op -> G(t), older, is covered for free).
// 256-thread blocks (4 waves), wave-per-triplet, 16 triplets/wave.
// LDS = 4 waves x 4 slots x 512 floats = 32768 B -> 5 blocks/CU.
// ---------------------------------------------------------------------------
__device__ __forceinline__ float dpp_fmax16(float x) {
    int o;
    o = __builtin_amdgcn_update_dpp(0, __float_as_int(x), 0x121, 0xF, 0xF, true);
    x = fmaxf(x, __int_as_float(o));
    o = __builtin_amdgcn_update_dpp(0, __float_as_int(x), 0x122, 0xF, 0xF, true);
    x = fmaxf(x, __int_as_float(o));
    o = __builtin_amdgcn_update_dpp(0, __float_as_int(x), 0x124, 0xF, 0xF, true);
    x = fmaxf(x, __int_as_float(o));
    o = __builtin_amdgcn_update_dpp(0, __float_as_int(x), 0x128, 0xF, 0xF, true);
    x = fmaxf(x, __int_as_float(o));
    return x;
}

__device__ __forceinline__ int dpp_imin16(int x) {
    int o;
    o = __builtin_amdgcn_update_dpp(0, x, 0x121, 0xF, 0xF, true); x = min(x, o);
    o = __builtin_amdgcn_update_dpp(0, x, 0x122, 0xF, 0xF, true); x = min(x, o);
    o = __builtin_amdgcn_update_dpp(0, x, 0x124, 0xF, 0xF, true); x = min(x, o);
    o = __builtin_amdgcn_update_dpp(0, x, 0x128, 0xF, 0xF, true); x = min(x, o);
    return x;
}

__device__ __forceinline__ float wave_fmax(float x) {
    x = dpp_fmax16(x);
    x = fmaxf(x, __shfl_xor(x, 16, 64));
    x = fmaxf(x, __shfl_xor(x, 32, 64));
    return x;
}

__device__ __forceinline__ int wave_imin(int x) {
    x = dpp_imin16(x);
    x = min(x, __shfl_xor(x, 16, 64));
    x = min(x, __shfl_xor(x, 32, 64));
    return x;
}

// async 1KB row: lane l moves bytes [16l,16l+16) of src to lds_dst + 16l
__device__ __forceinline__ void ld_row_async(const float* src, const float* lds_dst, int lane) {
    typedef __attribute__((address_space(3))) uint32_t as3_u32;
    typedef const __attribute__((address_space(1))) uint32_t as1_u32;
    __builtin_amdgcn_global_load_lds((as1_u32*)(src + 4 * lane),
                                     (as3_u32*)(uint32_t)(uintptr_t)lds_dst,
                                     16, 0, 0);
}

// select element c (0..3, wave-uniform) of a float4
__device__ __forceinline__ float sel4(const float4 v, int c) {
    const float lo = (c & 1) ? v.y : v.x;
    const float hi = (c & 1) ? v.w : v.z;
    return (c & 2) ? hi : lo;
}

__global__ __launch_bounds__(256)
void ghhc_fused_kernel(const float* __restrict__ Da, const float* __restrict__ Db,
                       const float* __restrict__ Dc, const float* __restrict__ Dd,
                       const int* __restrict__ ta, const int* __restrict__ tb,
                       const int* __restrict__ tc, const int* __restrict__ td,
                       const float* __restrict__ ga, const float* __restrict__ gb,
                       const float* __restrict__ gc, const float* __restrict__ gd,
                       int Ta, int Tb, int Tc, int Td,
                       float sa, float sb, float sc_, float sd,
                       int nba, int nbb, int nbc,
                       float* __restrict__ out)
{
    const int tid  = threadIdx.x;
    const int w    = tid >> 6;
    const int lane = tid & 63;

    const int b = blockIdx.x;
    const float* D; const int* tr; const float* g; int Tt; float sc; int lb;
    if (b < nba)                   { D = Da; tr = ta; g = ga; Tt = Ta; sc = sa;  lb = b; }
    else if (b < nba + nbb)        { D = Db; tr = tb; g = gb; Tt = Tb; sc = sb;  lb = b - nba; }
    else if (b < nba + nbb + nbc)  { D = Dc; tr = tc; g = gc; Tt = Tc; sc = sc_; lb = b - nba - nbb; }
    else                           { D = Dd; tr = td; g = gd; Tt = Td; sc = sd;  lb = b - nba - nbb - nbc; }

    const int tstart = lb * 64 + w * 16;   // this wave's 16 consecutive triplets

    // lanes 0-15 hold the 16 triplet indices (lanes 16+ replicate)
    int tl = tstart + (lane & 15);
    tl = (tl < Tt) ? tl : (Tt - 1);
    const int idxi = tr[tl];
    const int idxj = tr[Tt + tl];
    const int idxk = tr[2 * Tt + tl];

    // per-wave LDS: 4 g-slots x (2 rows x 256 floats) = 8 KB/wave
    __shared__ __align__(16) float sbuf[4 * 4 * 512];   // 32768 B
    float* const wbase = sbuf + w * 2048;

    // D register rotating buffers: depth 3 x 3 rows x float4 = 36 VGPR
    float4 bdi[3], bdj[3], bdk[3];

    #define ISSUE_D(IT) { \
        const int i_ = __shfl(idxi, (IT) & 15, 64); \
        const int j_ = __shfl(idxj, (IT) & 15, 64); \
        const int k_ = __shfl(idxk, (IT) & 15, 64); \
        bdi[(IT) % 3] = ((const float4*)(D + (size_t)i_ * NPROX))[lane]; \
        bdj[(IT) % 3] = ((const float4*)(D + (size_t)j_ * NPROX))[lane]; \
        bdk[(IT) % 3] = ((const float4*)(D + (size_t)k_ * NPROX))[lane]; \
    }

    #define ISSUE_G(IT) { \
        const int t_  = tstart + (IT); \
        const int te_ = (t_ < Tt) ? t_ : (Tt - 1); \
        float* B_ = wbase + ((IT) % 4) * 512; \
        ld_row_async(g + (size_t)te_ * NPROX,         B_ +   0, lane); \
        ld_row_async(g + ((size_t)Tt + te_) * NPROX,  B_ + 256, lane); \
    }

    float acc = 0.0f;

    // prologue: G(0..2) [HBM stream, longest lead], then D(0), D(1).
    // sched_barrier fences pin the FIFO order the vmcnt table assumes.
    ISSUE_G(0); ISSUE_G(1); ISSUE_G(2);
    __builtin_amdgcn_sched_barrier(0);
    ISSUE_D(0);
    __builtin_amdgcn_sched_barrier(0);
    ISSUE_D(1);
    __builtin_amdgcn_sched_barrier(0);

    // per-step: issue D(t+2), fence, issue G(t+3), wait (counted), fence,
    // then consume tile t (g from LDS, D from registers).
    #define STEP(IT, VM) { \
        if ((IT) + 2 < 16) ISSUE_D((IT) + 2) \
        __builtin_amdgcn_sched_barrier(0); \
        if ((IT) + 3 < 16) ISSUE_G((IT) + 3) \
        asm volatile("s_waitcnt vmcnt(" VM ")" ::: "memory"); \
        __builtin_amdgcn_sched_barrier(0); \
        const float* B_ = wbase + ((IT) % 4) * 512; \
        const float4 q0 = ((const float4*)(B_ +   0))[lane]; \
        const float4 q1 = ((const float4*)(B_ + 256))[lane]; \
        const float4 di = bdi[(IT) % 3]; \
        const float4 dj = bdj[(IT) % 3]; \
        const float4 dk = bdk[(IT) % 3]; \
        float S0, S1, S2, S3, U0, U1, U2, U3; \
        { float m1, m2; \
          m1 = fmaxf(di.x, dj.x); S0 = fmaf(m1, -10.0f, q0.x); m2 = fmaxf(dk.x, m1); U0 = fmaf(m2, -10.0f, q1.x); \
          m1 = fmaxf(di.y, dj.y); S1 = fmaf(m1, -10.0f, q0.y); m2 = fmaxf(dk.y, m1); U1 = fmaf(m2, -10.0f, q1.y); \
          m1 = fmaxf(di.z, dj.z); S2 = fmaf(m1, -10.0f, q0.z); m2 = fmaxf(dk.z, m1); U2 = fmaf(m2, -10.0f, q1.z); \
          m1 = fmaxf(di.w, dj.w); S3 = fmaf(m1, -10.0f, q0.w); m2 = fmaxf(dk.w, m1); U3 = fmaf(m2, -10.0f, q1.w); } \
        const float gvA = wave_fmax(fmaxf(fmaxf(S0, S1), fmaxf(S2, S3))); \
        const float gvB = wave_fmax(fmaxf(fmaxf(U0, U1), fmaxf(U2, U3))); \
        int slA = 4, slB = 4; \
        slA = (S3 == gvA) ? 3 : slA; slA = (S2 == gvA) ? 2 : slA; \
        slA = (S1 == gvA) ? 1 : slA; slA = (S0 == gvA) ? 0 : slA; \
        slB = (U3 == gvB) ? 3 : slB; slB = (U2 == gvB) ? 2 : slB; \
        slB = (U1 == gvB) ? 1 : slB; slB = (U0 == gvB) ? 0 : slB; \
        const int eA = (slA < 4) ? ((lane << 2) | slA) : 1024; \
        const int eB = (slB < 4) ? ((lane << 2) | slB) : 1024; \
        const int Ag = wave_imin(eA); \
        const int Bg = wave_imin(eB); \
        const int lA = Ag >> 2, cA = Ag & 3; \
        const int lB = Bg >> 2, cB = Bg & 3; \
        const float diA = __shfl(sel4(di, cA), lA, 64); \
        const float djA = __shfl(sel4(dj, cA), lA, 64); \
        const float dkA = __shfl(sel4(dk, cA), lA, 64); \
        const float diB = __shfl(sel4(di, cB), lB, 64); \
        const float djB = __shfl(sel4(dj, cB), lB, 64); \
        const float dkB = __shfl(sel4(dk, cB), lB, 64); \
        const float hc = fmaxf(diA - diB + MRG, 0.0f) \
                       + fmaxf(djA - djB + MRG, 0.0f) \
                       + fmaxf(dkB - dkA + MRG, 0.0f); \
        acc += (((tstart + (IT)) < Tt) && (Ag != Bg) && lane == 0) ? hc * sc : 0.0f; \
    }

    // vmcnt(N): N = #VMEM ops issued after D(t)'s last load (in-order FIFO).
    // prologue [G0 G1 G2 | D0 | D1] = 12 ops; step t issues
    // D(t+2) [t<=13] (3 ops) then G(t+3) [t<=12] (2 ops).
    STEP(0,"8")   STEP(1,"10")  STEP(2,"12")  STEP(3,"12")
    STEP(4,"12")  STEP(5,"12")  STEP(6,"12")  STEP(7,"12")
    STEP(8,"12")  STEP(9,"12")  STEP(10,"12") STEP(11,"12")
    STEP(12,"12") STEP(13,"10") STEP(14,"5")  STEP(15,"0")

    #undef STEP
    #undef ISSUE_D
    #undef ISSUE_G

    // block reduction: reuse sbuf (all DMAs drained by step 15's vmcnt(0))
    if (lane == 0) wbase[0] = acc;
    __syncthreads();
    if (tid == 0)
        atomicAdd(out, sbuf[0] + sbuf[2048] + sbuf[4096] + sbuf[6144]);
}

// ---------------------------------------------------------------------------
extern "C" void kernel_launch(void* const* d_in, const int* in_sizes, int n_in,
                              void* d_out, int out_size, void* d_ws, size_t ws_size,
                              hipStream_t stream)
{
    const float* z_s  = (const float*)d_in[0];
    const float* t_s  = (const float*)d_in[1];
    const float* lcas = (const float*)d_in[3];
    const int* trip1 = (const int*)d_in[4];
    const int* trip2 = (const int*)d_in[5];
    const int* trip3 = (const int*)d_in[6];
    const int* trip4 = (const int*)d_in[7];
    const float* g1 = (const float*)d_in[8];
    const float* g2 = (const float*)d_in[9];
    const float* g3 = (const float*)d_in[10];
    const float* g4 = (const float*)d_in[11];
    float* out = (float*)d_out;
    float* ws  = (float*)d_ws;

    const int T1 = in_sizes[4] / 3;   // 51200
    const int T2 = in_sizes[5] / 3;   // 12800
    const int T3 = in_sizes[6] / 3;   // 51200
    const int T4 = in_sizes[7] / 3;   // 12800
    const int BS = in_sizes[0] / DIM; // 1024
    const int nb1 = BS / 4;

    to_poincare_kernel<<<NPROX, 128, 0, stream>>>(lcas, ws, out);

    dist_all_kernel<<<2 * nb1 + 64, 256, 0, stream>>>(z_s, t_s, ws, nb1);

    // 64 triplets per block (4 waves x 16 triplets each)
    const int nbA = (T1 + 63) / 64;   // 800
    const int nbB = (T2 + 63) / 64;   // 200
    const int nbC = (T3 + 63) / 64;   // 800
    const int nbD = (T4 + 63) / 64;   // 200
    ghhc_fused_kernel<<<nbA + nbB + nbC + nbD, 256, 0, stream>>>(
        ws + OFF_D1, ws + OFF_D2, ws + OFF_D3, ws + OFF_D2,
        trip1, trip2, trip3, trip4,
        g1, g2, g3, g4,
        T1, T2, T3, T4,
        1.0f / (float)T1, 1.0f / (float)T2, 1.0f / (float)T3, 1.0f / (float)T4,
        nbA, nbB, nbC,
        out);
}